// Round 7
// baseline (339.993 us; speedup 1.0000x reference)
//
#include <hip/hip_runtime.h>
#include <hip/hip_bf16.h>
#include <hip/hip_fp8.h>
#include <math.h>

typedef unsigned short u16;
typedef unsigned char u8;
typedef unsigned int u32;
typedef long i64;
typedef __bf16 bf16x8 __attribute__((ext_vector_type(8)));
typedef float f32x4 __attribute__((ext_vector_type(4)));
typedef i64 i64x2 __attribute__((ext_vector_type(2)));

#define MFMA16(a, b, c) __builtin_amdgcn_mfma_f32_16x16x32_bf16(a, b, c, 0, 0, 0)
#define MFMA8(a, b, c) __builtin_amdgcn_mfma_f32_16x16x32_fp8_fp8(a, b, c, 0, 0, 0)

__device__ __forceinline__ u16 f2b(float f) {
    __bf16 h = (__bf16)f;
    return __builtin_bit_cast(u16, h);
}

// HW packed fp8-e4m3 convert (RNE): bytes [7:0]=fp8(a), [15:8]=fp8(b)
__device__ __forceinline__ u32 cvt2fp8(float a, float b) {
    u32 d;
    asm("v_cvt_pk_fp8_f32 %0, %1, %2" : "=v"(d) : "v"(a), "v"(b));
    return d;
}

// async global->LDS, 16B per lane. LDS dest = wave-uniform base + lane*16.
__device__ __forceinline__ void gld16(const void* g, void* l) {
    __builtin_amdgcn_global_load_lds(
        (const __attribute__((address_space(1))) unsigned int*)g,
        (__attribute__((address_space(3))) unsigned int*)l, 16, 0, 0);
}

// fp8 k-interleave within each 64-k group: k = s*32 + q*8 + j  ->  pos = q*16 + s*8 + j.
// Makes one lane's two BK=64 k-fragments a single aligned 16-B LDS read at 64-B row
// stride (m97-proven conflict class) instead of two stride-32 b64 reads (4-way).

// ---------------- fused transpose + convert of all six weights ----------------
// Wq..W1 -> bf16 [out][in]; W2 -> fp8 e4m3 scaled x64, k-interleaved.
__global__ __launch_bounds__(256) void transpose_all(
    const float* __restrict__ Wq, const float* __restrict__ Wk,
    const float* __restrict__ Wv, const float* __restrict__ Wo,
    const float* __restrict__ W1, const float* __restrict__ W2, u16* __restrict__ wqkvT,
    u16* __restrict__ woT, u16* __restrict__ w1T, u8* __restrict__ w2T8) {
    __shared__ float tile[32][33];
    int t = blockIdx.x;
    const float* in;
    u16* out = nullptr;
    int R, C;
    bool isf8 = false;
    if (t < 3072) {
        int m = t >> 10;
        t &= 1023;
        in = m == 0 ? Wq : (m == 1 ? Wk : Wv);
        out = wqkvT + m * 1048576;
        R = 1024; C = 1024;
    } else if (t < 4096) {
        t -= 3072; in = Wo; out = woT; R = 1024; C = 1024;
    } else if (t < 8192) {
        t -= 4096; in = W1; out = w1T; R = 1024; C = 4096;
    } else {
        t -= 8192; in = W2; R = 4096; C = 1024; isf8 = true;
    }
    int tilesX = C >> 5;
    int c0 = (t % tilesX) * 32, r0 = (t / tilesX) * 32;
    int tx = threadIdx.x, ty = threadIdx.y;
#pragma unroll
    for (int i = 0; i < 4; i++)
        tile[ty + i * 8][tx] = in[(size_t)(r0 + ty + i * 8) * C + c0 + tx];
    __syncthreads();
    if (isf8) {
        // k = r0+tx (r0 mult of 32, tx<32): pos = base + q*16 + s*8 + j
        int pos = (r0 & ~63) + (tx >> 3) * 16 + ((r0 >> 5) & 1) * 8 + (tx & 7);
        u32 p01 = cvt2fp8(tile[tx][ty] * 64.0f, tile[tx][ty + 8] * 64.0f);
        u32 p23 = cvt2fp8(tile[tx][ty + 16] * 64.0f, tile[tx][ty + 24] * 64.0f);
        w2T8[(size_t)(c0 + ty) * 4096 + pos] = (u8)p01;
        w2T8[(size_t)(c0 + ty + 8) * 4096 + pos] = (u8)(p01 >> 8);
        w2T8[(size_t)(c0 + ty + 16) * 4096 + pos] = (u8)p23;
        w2T8[(size_t)(c0 + ty + 24) * 4096 + pos] = (u8)(p23 >> 8);
    } else {
#pragma unroll
        for (int i = 0; i < 4; i++)
            out[(size_t)(c0 + ty + i * 8) * R + r0 + tx] = f2b(tile[tx][ty + i * 8]);
    }
}

// ---------------- LayerNorm: fp32 [4096][1024] -> bf16 [4096][1024] ----------------
__global__ __launch_bounds__(256) void ln_kernel(const float* __restrict__ x,
                                                 const float* __restrict__ g,
                                                 const float* __restrict__ b,
                                                 u16* __restrict__ out) {
    int row = blockIdx.x;
    int tid = threadIdx.x;
    const float* xr = x + (size_t)row * 1024;
    float4 v = ((const float4*)xr)[tid];
    float s = v.x + v.y + v.z + v.w;
    float s2 = v.x * v.x + v.y * v.y + v.z * v.z + v.w * v.w;
#pragma unroll
    for (int off = 32; off > 0; off >>= 1) {
        s += __shfl_xor(s, off);
        s2 += __shfl_xor(s2, off);
    }
    __shared__ float ps[4], ps2[4];
    int wid = tid >> 6;
    if ((tid & 63) == 0) { ps[wid] = s; ps2[wid] = s2; }
    __syncthreads();
    s = ps[0] + ps[1] + ps[2] + ps[3];
    s2 = ps2[0] + ps2[1] + ps2[2] + ps2[3];
    float mu = s * (1.0f / 1024.0f);
    float var = s2 * (1.0f / 1024.0f) - mu * mu;
    float rs = rsqrtf(var + 1e-5f);
    int c = tid * 4;
    ushort4 o;
    o.x = f2b((v.x - mu) * rs * g[c + 0] + b[c + 0]);
    o.y = f2b((v.y - mu) * rs * g[c + 1] + b[c + 1]);
    o.z = f2b((v.z - mu) * rs * g[c + 2] + b[c + 2]);
    o.w = f2b((v.w - mu) * rs * g[c + 3] + b[c + 3]);
    ((ushort4*)(out + (size_t)row * 1024))[tid] = o;
}

// ---------------- bf16 MFMA GEMM 128x128 (QKV / W1-GELU) ----------------
// For the QKV kernel's V-third (n0>=2048), operands are swapped in the MFMA so the
// accumulator holds V^T; the epilogue writes the kv-permuted VbT layout directly
// (pi(c) = (c&15)*2 + (c>>4) within each 32-block of s) -- no separate vtrans pass.
#define EPI_QKV 0
#define EPI_RESID 1
#define EPI_GELU 2

__device__ __forceinline__ void gemm_stage(const u16* __restrict__ A,
                                           const u16* __restrict__ BT,
                                           u16 (&Asb)[128][32], u16 (&Bsb)[128][32],
                                           int m0, int n0, int K, int k0, int sr, int sdc,
                                           int wb) {
    gld16(&A[(size_t)(m0 + sr) * K + k0 + sdc], &Asb[0][0] + wb);
    gld16(&A[(size_t)(m0 + 64 + sr) * K + k0 + sdc], &Asb[0][0] + 2048 + wb);
    gld16(&BT[(size_t)(n0 + sr) * K + k0 + sdc], &Bsb[0][0] + wb);
    gld16(&BT[(size_t)(n0 + 64 + sr) * K + k0 + sdc], &Bsb[0][0] + 2048 + wb);
}

__device__ __forceinline__ void gemm_compute(const u16 (&Asb)[128][32],
                                             const u16 (&Bsb)[128][32], f32x4 (&acc)[4][4],
                                             int wm, int wn, int quad, int c15,
                                             bool swapV) {
    bf16x8 af[4], bfr[4];
#pragma unroll
    for (int i = 0; i < 4; i++) af[i] = *(const bf16x8*)&Asb[wm + i * 16 + c15][quad * 8];
#pragma unroll
    for (int j = 0; j < 4; j++) bfr[j] = *(const bf16x8*)&Bsb[wn + j * 16 + c15][quad * 8];
    if (!swapV) {
#pragma unroll
        for (int i = 0; i < 4; i++)
#pragma unroll
            for (int j = 0; j < 4; j++) acc[i][j] = MFMA16(af[i], bfr[j], acc[i][j]);
    } else {
        // acc[i][j] = (W^T h^T) tile: rows = d (Bs frag i), cols = s (As frag j)
#pragma unroll
        for (int i = 0; i < 4; i++)
#pragma unroll
            for (int j = 0; j < 4; j++) acc[i][j] = MFMA16(bfr[i], af[j], acc[i][j]);
    }
}

template <int EPI>
__global__ __launch_bounds__(256) void gemm_kernel(const u16* __restrict__ A,
                                                   const u16* __restrict__ BT,
                                                   const float* __restrict__ bias0,
                                                   const float* __restrict__ bias1,
                                                   const float* __restrict__ bias2,
                                                   void* __restrict__ outp,
                                                   const float* __restrict__ resid,
                                                   int N, int K) {
    __shared__ __align__(16) u16 As0[128][32], Bs0[128][32];
    __shared__ __align__(16) u16 As1[128][32], Bs1[128][32];
    const int tid = threadIdx.x;
    const int m0 = blockIdx.y * 128, n0 = blockIdx.x * 128;
    const int w = tid >> 6, lid = tid & 63, quad = lid >> 4, c15 = lid & 15;
    const int wm = (w >> 1) * 64, wn = (w & 1) * 64;
    const int sr = tid >> 2, sdc = (tid & 3) * 8;
    const int wb = (tid & 192) * 8;
    const bool swapV = (EPI == EPI_QKV) && (n0 >= 2048);

    f32x4 acc[4][4] = {};

    gemm_stage(A, BT, As0, Bs0, m0, n0, K, 0, sr, sdc, wb);
    const int KT = K >> 5;  // even (32 or 128)
    for (int kt = 0; kt < KT; kt += 2) {
        __syncthreads();
        gemm_stage(A, BT, As1, Bs1, m0, n0, K, (kt + 1) << 5, sr, sdc, wb);
        gemm_compute(As0, Bs0, acc, wm, wn, quad, c15, swapV);
        __syncthreads();
        if (kt + 2 < KT) gemm_stage(A, BT, As0, Bs0, m0, n0, K, (kt + 2) << 5, sr, sdc, wb);
        gemm_compute(As1, Bs1, acc, wm, wn, quad, c15, swapV);
    }

    const int which = n0 >> 10;
    const float* bias = (EPI == EPI_QKV) ? (which == 0 ? bias0 : (which == 1 ? bias1 : bias2))
                                         : bias0;

    if (EPI == EPI_QKV && swapV) {
        // acc = V^T tile: d = (n0-2048)+wn+i*16+quad*4+r, s = m0+wm+j*16+c15.
        // Store to VbT [bh][64][2048'] (kv-permuted): VbT = outp + 3*4194304 u16.
        u16* vbt = (u16*)outp + (size_t)3 * 4194304;
#pragma unroll
        for (int i = 0; i < 4; i++) {
#pragma unroll
            for (int j = 0; j < 4; j++) {
                int sg = m0 + wm + j * 16 + c15;
                int bbq = sg >> 11, ss = sg & 2047;
                int col = (ss & ~31) + (ss & 15) * 2 + ((ss >> 4) & 1);
#pragma unroll
                for (int r = 0; r < 4; r++) {
                    int dg = (n0 - 2048) + wn + i * 16 + quad * 4 + r;
                    float v = acc[i][j][r] + bias[dg];
                    int hh = dg >> 6, dd = dg & 63;
                    vbt[(((size_t)(bbq * 16 + hh) * 64 + dd) << 11) + col] = f2b(v);
                }
            }
        }
        return;
    }

    // hoisted k-interleave positions for the GELU->fp8 epilogue
    int posj[4];
    if (EPI == EPI_GELU) {
#pragma unroll
        for (int j = 0; j < 4; j++) {
            int gc = n0 + wn + j * 16 + c15;
            int g = gc & 63;
            posj[j] = (gc & ~63) + ((g >> 3) & 3) * 16 + ((g >> 5) & 1) * 8 + (g & 7);
        }
    }

#pragma unroll
    for (int i = 0; i < 4; i++) {
#pragma unroll
        for (int j = 0; j < 4; j++) {
            if (EPI == EPI_GELU) {
                int gc = n0 + wn + j * 16 + c15;
                float vv[4];
#pragma unroll
                for (int r = 0; r < 4; r++) {
                    // gelu(v) = v * sigmoid(2u), u = v*(c1 + c2 v^2)  [tanh form]
                    float v = acc[i][j][r] + bias[gc];
                    float t = v * v;
                    float u2 = v * (1.59576912f + 0.07135482f * t);
                    float e = __expf(u2);
                    float q = __frcp_rn(e + 1.0f);
                    vv[r] = v - v * q;
                }
                u32 p01 = cvt2fp8(vv[0], vv[1]);
                u32 p23 = cvt2fp8(vv[2], vv[3]);
                int gr = m0 + wm + i * 16 + quad * 4;
                u8* dst = (u8*)outp + (size_t)gr * N + posj[j];
                dst[0] = (u8)p01;
                dst[N] = (u8)(p01 >> 8);
                dst[2 * N] = (u8)p23;
                dst[3 * N] = (u8)(p23 >> 8);
            } else {
#pragma unroll
                for (int r = 0; r < 4; r++) {
                    int gr = m0 + wm + i * 16 + quad * 4 + r;
                    int gc = n0 + wn + j * 16 + c15;
                    if (EPI == EPI_QKV) {
                        int lc = gc & 1023;
                        float v = acc[i][j][r] + bias[lc];
                        int bb = gr >> 11, ss = gr & 2047, hh = lc >> 6, dd = lc & 63;
                        u16* qkv_dst = (u16*)outp + (size_t)which * 4194304;
                        qkv_dst[((size_t)((bb * 16 + hh) * 2048 + ss)) * 64 + dd] = f2b(v);
                    } else {  // EPI_RESID
                        float v = acc[i][j][r] + bias[gc];
                        ((float*)outp)[(size_t)gr * N + gc] =
                            resid[(size_t)gr * N + gc] + v;
                    }
                }
            }
        }
    }
}

// ---------------- bf16 MFMA GEMM 128x64 (O-proj): grid 512 = 2 blocks/CU ----------------
__global__ __launch_bounds__(256) void gemm64_kernel(const u16* __restrict__ A,
                                                     const u16* __restrict__ BT,
                                                     const float* __restrict__ bias,
                                                     float* __restrict__ outp,
                                                     const float* __restrict__ resid,
                                                     int N, int K) {
    __shared__ __align__(16) u16 As0[128][32], Bs0[64][32];
    __shared__ __align__(16) u16 As1[128][32], Bs1[64][32];
    const int tid = threadIdx.x;
    const int m0 = blockIdx.y * 128, n0 = blockIdx.x * 64;
    const int w = tid >> 6, lid = tid & 63, quad = lid >> 4, c15 = lid & 15;
    const int wm = (w >> 1) * 64, wn = (w & 1) * 32;
    const int sr = tid >> 2, sdc = (tid & 3) * 8;
    const int wb = (tid & 192) * 8;

    f32x4 acc[4][2] = {};

    auto stage = [&](u16 (&Asb)[128][32], u16 (&Bsb)[64][32], int k0) {
        gld16(&A[(size_t)(m0 + sr) * K + k0 + sdc], &Asb[0][0] + wb);
        gld16(&A[(size_t)(m0 + 64 + sr) * K + k0 + sdc], &Asb[0][0] + 2048 + wb);
        gld16(&BT[(size_t)(n0 + sr) * K + k0 + sdc], &Bsb[0][0] + wb);
    };
    auto compute = [&](const u16 (&Asb)[128][32], const u16 (&Bsb)[64][32]) {
        bf16x8 af[4], bfr[2];
#pragma unroll
        for (int i = 0; i < 4; i++) af[i] = *(const bf16x8*)&Asb[wm + i * 16 + c15][quad * 8];
#pragma unroll
        for (int j = 0; j < 2; j++) bfr[j] = *(const bf16x8*)&Bsb[wn + j * 16 + c15][quad * 8];
#pragma unroll
        for (int i = 0; i < 4; i++)
#pragma unroll
            for (int j = 0; j < 2; j++) acc[i][j] = MFMA16(af[i], bfr[j], acc[i][j]);
    };

    stage(As0, Bs0, 0);
    const int KT = K >> 5;
    for (int kt = 0; kt < KT; kt += 2) {
        __syncthreads();
        stage(As1, Bs1, (kt + 1) << 5);
        compute(As0, Bs0);
        __syncthreads();
        if (kt + 2 < KT) stage(As0, Bs0, (kt + 2) << 5);
        compute(As1, Bs1);
    }

#pragma unroll
    for (int i = 0; i < 4; i++) {
#pragma unroll
        for (int j = 0; j < 2; j++) {
#pragma unroll
            for (int r = 0; r < 4; r++) {
                int gr = m0 + wm + i * 16 + quad * 4 + r;
                int gc = n0 + wn + j * 16 + c15;
                float v = acc[i][j][r] + bias[gc];
                outp[(size_t)gr * N + gc] = resid[(size_t)gr * N + gc] + v;
            }
        }
    }
}

// ---------------- fp8 MFMA GEMM (W2): out = resid + mid8 @ w2T8^T /64 + bias --------
// Tile 128x64, BK=64 (k-interleaved operands -> b128 frag reads at 64-B row stride),
// grid 512 = 2 blocks/CU, dbuf-2 + __syncthreads.
__global__ __launch_bounds__(256) void gemm_fp8_kernel(const u8* __restrict__ A,
                                                       const u8* __restrict__ BT,
                                                       const float* __restrict__ bias,
                                                       float* __restrict__ outp,
                                                       const float* __restrict__ resid,
                                                       int N, int K) {
    __shared__ __align__(16) u8 As0[128][64], Bs0[64][64];
    __shared__ __align__(16) u8 As1[128][64], Bs1[64][64];
    const int tid = threadIdx.x;
    const int m0 = blockIdx.y * 128, n0 = blockIdx.x * 64;
    const int w = tid >> 6, lid = tid & 63, quad = lid >> 4, c15 = lid & 15;
    const int wm = (w >> 1) * 64, wn = (w & 1) * 32;
    const int sr = tid >> 2, sdc = (tid & 3) * 16;
    const int wbB = (tid & 192) * 16;  // wave's 1024-B LDS chunk (bytes)

    f32x4 acc[4][2] = {};

    auto stage = [&](u8 (&Asb)[128][64], u8 (&Bsb)[64][64], int k0) {
        gld16(&A[(size_t)(m0 + sr) * K + k0 + sdc], &Asb[0][0] + wbB);
        gld16(&A[(size_t)(m0 + 64 + sr) * K + k0 + sdc], &Asb[0][0] + 4096 + wbB);
        gld16(&BT[(size_t)(n0 + sr) * K + k0 + sdc], &Bsb[0][0] + wbB);
    };
    auto compute = [&](const u8 (&Asb)[128][64], const u8 (&Bsb)[64][64]) {
        i64x2 af[4], bfr[2];
#pragma unroll
        for (int i = 0; i < 4; i++)
            af[i] = *(const i64x2*)&Asb[wm + i * 16 + c15][quad * 16];
#pragma unroll
        for (int j = 0; j < 2; j++)
            bfr[j] = *(const i64x2*)&Bsb[wn + j * 16 + c15][quad * 16];
#pragma unroll
        for (int s = 0; s < 2; s++)
#pragma unroll
            for (int i = 0; i < 4; i++)
#pragma unroll
                for (int j = 0; j < 2; j++)
                    acc[i][j] = MFMA8(af[i][s], bfr[j][s], acc[i][j]);
    };

    stage(As0, Bs0, 0);
    const int KT = K >> 6;  // 64
    for (int kt = 0; kt < KT; kt += 2) {
        __syncthreads();
        stage(As1, Bs1, (kt + 1) << 6);
        compute(As0, Bs0);
        __syncthreads();
        if (kt + 2 < KT) stage(As0, Bs0, (kt + 2) << 6);
        compute(As1, Bs1);
    }

#pragma unroll
    for (int i = 0; i < 4; i++) {
#pragma unroll
        for (int j = 0; j < 2; j++) {
#pragma unroll
            for (int r = 0; r < 4; r++) {
                int gr = m0 + wm + i * 16 + quad * 4 + r;
                int gc = n0 + wn + j * 16 + c15;
                float v = acc[i][j][r] * (1.0f / 64.0f) + bias[gc];  // w2 scaled x64
                outp[(size_t)gr * N + gc] = resid[(size_t)gr * N + gc] + v;
            }
        }
    }
}

// ---------------- causal flash attention: 64-q blocks, longest-first ----------------
// grid (32 bh, 32 q-tiles), qt = 31-by. Block = 4 waves x 16 q rows; kv-step 64;
// dbuf-2 K/V via gld16; no online max (LN'd inputs: scores O(2), exp safe).
__device__ __forceinline__ void attn_step(const u16 (&KB)[2][64][32],
                                          const u16 (&VB)[2][64][32],
                                          u16 (&Psw)[2][16][48], const bf16x8 (&aq)[2],
                                          f32x4 (&o)[4], float (&lsum)[4], int kv0,
                                          int qr0, int quad, int c15) {
    bf16x8 bk[4][2];
#pragma unroll
    for (int nf = 0; nf < 4; nf++)
#pragma unroll
        for (int kd = 0; kd < 2; kd++)
            bk[nf][kd] = *(const bf16x8*)&KB[kd][nf * 16 + c15][quad * 8];
    f32x4 sf[4];
#pragma unroll
    for (int nf = 0; nf < 4; nf++) {
        f32x4 s = {};
        s = MFMA16(aq[0], bk[nf][0], s);
        s = MFMA16(aq[1], bk[nf][1], s);
        sf[nf] = s;
    }
    const bool domask = (kv0 + 63 > qr0);
    if (domask) {
#pragma unroll
        for (int r = 0; r < 4; r++) {
            int rowg = qr0 + quad * 4 + r;
#pragma unroll
            for (int nf = 0; nf < 4; nf++) {
                float p = (kv0 + nf * 16 + c15 <= rowg) ? __expf(sf[nf][r] * 0.125f) : 0.0f;
                sf[nf][r] = p;
                lsum[r] += p;
            }
        }
    } else {
#pragma unroll
        for (int r = 0; r < 4; r++)
#pragma unroll
            for (int nf = 0; nf < 4; nf++) {
                float p = __expf(sf[nf][r] * 0.125f);
                sf[nf][r] = p;
                lsum[r] += p;
            }
    }
    // P: C-layout -> A-layout via LDS, kv-permuted to pack b32 writes
#pragma unroll
    for (int ks = 0; ks < 2; ks++)
#pragma unroll
        for (int r = 0; r < 4; r++) {
            u32 pk = (u32)f2b(sf[2 * ks][r]) | ((u32)f2b(sf[2 * ks + 1][r]) << 16);
            *(u32*)&Psw[ks][quad * 4 + r][2 * c15] = pk;
        }
    asm volatile("s_waitcnt lgkmcnt(0)" ::: "memory");  // same-wave Ps write->read
    bf16x8 ap[2];
#pragma unroll
    for (int ks = 0; ks < 2; ks++) ap[ks] = *(const bf16x8*)&Psw[ks][c15][quad * 8];
#pragma unroll
    for (int df = 0; df < 4; df++) {
        bf16x8 bv0 = *(const bf16x8*)&VB[0][df * 16 + c15][quad * 8];
        bf16x8 bv1 = *(const bf16x8*)&VB[1][df * 16 + c15][quad * 8];
        o[df] = MFMA16(ap[0], bv0, o[df]);
        o[df] = MFMA16(ap[1], bv1, o[df]);
    }
}

__global__ __launch_bounds__(256) void attn_kernel(const u16* __restrict__ Q,
                                                   const u16* __restrict__ Kb,
                                                   const u16* __restrict__ VbT,
                                                   u16* __restrict__ attO) {
    __shared__ __align__(16) u16 Ks[2][2][64][32];  // [buf][d-half][kv][d32]
    __shared__ __align__(16) u16 Vs[2][2][64][32];  // [buf][kv-half][d][kv32]
    __shared__ __align__(16) u16 Ps[4][2][16][48];

    const int tid = threadIdx.x;
    const int bh = blockIdx.x;
    const int qt = 31 - blockIdx.y;  // longest q-tiles dispatched first
    const int q0 = qt * 64;
    const size_t base = (size_t)bh * 2048 * 64;
    const u16* Qp = Q + base;
    const u16* Kp = Kb + base;
    const u16* Vp = VbT + (size_t)bh * 64 * 2048;
    const int w = tid >> 6, lane = tid & 63, quad = lane >> 4, c15 = lane & 15;
    const int qr0 = q0 + w * 16;
    const int sr = tid >> 2, sdc = (tid & 3) * 8;
    const int wb = (tid & 192) * 8;
    const int bb = bh >> 4, hh = bh & 15;

#define ATTN_STAGE(bi, kvo)                                                             \
    do {                                                                                \
        gld16(&Kp[(size_t)((kvo) + sr) * 64 + sdc], &Ks[bi][0][0][0] + wb);             \
        gld16(&Kp[(size_t)((kvo) + sr) * 64 + 32 + sdc], &Ks[bi][0][0][0] + 2048 + wb); \
        gld16(&Vp[(size_t)sr * 2048 + (kvo) + sdc], &Vs[bi][0][0][0] + wb);             \
        gld16(&Vp[(size_t)sr * 2048 + (kvo) + 32 + sdc], &Vs[bi][0][0][0] + 2048 + wb); \
    } while (0)

    bf16x8 aq[2];
#pragma unroll
    for (int ks = 0; ks < 2; ks++)
        aq[ks] = *(const bf16x8*)&Qp[(size_t)(qr0 + c15) * 64 + ks * 32 + quad * 8];

    f32x4 o[4] = {};
    float lsum[4] = {};
    const int steps = qt + 1;

    ATTN_STAGE(0, 0);
    for (int s = 0; s < steps; s++) {
        __syncthreads();
        if (s + 1 < steps) ATTN_STAGE((s + 1) & 1, (s + 1) << 6);
        attn_step(Ks[s & 1], Vs[s & 1], Ps[w], aq, o, lsum, s << 6, qr0, quad, c15);
    }

#pragma unroll
    for (int r = 0; r < 4; r++) {
        float l = lsum[r];
#pragma unroll
        for (int off = 1; off < 16; off <<= 1) l += __shfl_xor(l, off);
        float inv = 1.0f / l;
        int sg = qr0 + quad * 4 + r;
        size_t rowoff = ((size_t)(bb * 2048 + sg)) * 1024 + hh * 64;
#pragma unroll
        for (int df = 0; df < 4; df++) attO[rowoff + df * 16 + c15] = f2b(o[df][r] * inv);
    }
#undef ATTN_STAGE
}

// ---------------- launcher ----------------
extern "C" void kernel_launch(void* const* d_in, const int* in_sizes, int n_in,
                              void* d_out, int out_size, void* d_ws, size_t ws_size,
                              hipStream_t stream) {
    const float* x = (const float*)d_in[0];
    const float* ln1g = (const float*)d_in[1];
    const float* ln1b = (const float*)d_in[2];
    const float* Wq = (const float*)d_in[3];
    const float* bq = (const float*)d_in[4];
    const float* Wk = (const float*)d_in[5];
    const float* bk = (const float*)d_in[6];
    const float* Wv = (const float*)d_in[7];
    const float* bv = (const float*)d_in[8];
    const float* Wo = (const float*)d_in[9];
    const float* bo = (const float*)d_in[10];
    const float* ln2g = (const float*)d_in[11];
    const float* ln2b = (const float*)d_in[12];
    const float* W1 = (const float*)d_in[13];
    const float* b1 = (const float*)d_in[14];
    const float* W2 = (const float*)d_in[15];
    const float* b2 = (const float*)d_in[16];
    float* out = (float*)d_out;

    char* ws = (char*)d_ws;
    u16* wqkvT = (u16*)(ws + 0);              // [3072][1024] bf16, 6 MB
    u16* woT = (u16*)(ws + 6291456);          // [1024][1024], 2 MB
    u16* w1T = (u16*)(ws + 8388608);          // [4096][1024], 8 MB
    u8* w2T8 = (u8*)(ws + 16777216);          // [1024][4096] fp8 x64, k-interleaved, 4 MB
    u16* h = (u16*)(ws + 25165824);           // [4096][1024] bf16, 8 MB
    float* x1 = (float*)(ws + 33554432);      // [4096][1024] fp32, 16 MB
    u16* Qb = (u16*)(ws + 50331648);          // [32 bh][2048][64], 8 MB
    u16* Kb = (u16*)(ws + 58720256);          // 8 MB
    u16* aO = (u16*)(ws + 67108864);          // attn out, 8 MB
    u16* VbT = (u16*)(ws + 75497472);         // [32 bh][64][2048'] permuted, 8 MB
                                              // (= Qb + 3*4194304 u16 -- QKV V-third target)
    u8* mid8 = (u8*)(ws + 50331648);          // [4096][4096] fp8 k-interleaved, 16 MB

    transpose_all<<<12288, dim3(32, 8), 0, stream>>>(Wq, Wk, Wv, Wo, W1, W2, wqkvT, woT,
                                                     w1T, w2T8);

    ln_kernel<<<4096, 256, 0, stream>>>(x, ln1g, ln1b, h);

    // fused QKV projection; V-third writes VbT directly (transposed + permuted)
    gemm_kernel<EPI_QKV><<<dim3(24, 32), 256, 0, stream>>>(h, wqkvT, bq, bk, bv, Qb, nullptr,
                                                           3072, 1024);

    attn_kernel<<<dim3(32, 32), 256, 0, stream>>>(Qb, Kb, VbT, aO);

    gemm64_kernel<<<dim3(16, 32), 256, 0, stream>>>(aO, woT, bo, x1, x, 1024, 1024);

    ln_kernel<<<4096, 256, 0, stream>>>(x1, ln2g, ln2b, h);

    gemm_kernel<EPI_GELU><<<dim3(32, 32), 256, 0, stream>>>(h, w1T, b1, nullptr, nullptr, mid8,
                                                            nullptr, 4096, 1024);
    gemm_fp8_kernel<<<dim3(16, 32), 256, 0, stream>>>(mid8, w2T8, b2, out, x1, 1024, 4096);
}

// Round 8
// 323.077 us; speedup vs baseline: 1.0524x; 1.0524x over previous
//
#include <hip/hip_runtime.h>
#include <hip/hip_bf16.h>
#include <hip/hip_fp8.h>
#include <math.h>

typedef unsigned short u16;
typedef unsigned char u8;
typedef unsigned int u32;
typedef long i64;
typedef __bf16 bf16x8 __attribute__((ext_vector_type(8)));
typedef float f32x4 __attribute__((ext_vector_type(4)));
typedef i64 i64x2 __attribute__((ext_vector_type(2)));

#define MFMA16(a, b, c) __builtin_amdgcn_mfma_f32_16x16x32_bf16(a, b, c, 0, 0, 0)
#define MFMA8(a, b, c) __builtin_amdgcn_mfma_f32_16x16x32_fp8_fp8(a, b, c, 0, 0, 0)

__device__ __forceinline__ u16 f2b(float f) {
    __bf16 h = (__bf16)f;
    return __builtin_bit_cast(u16, h);
}

// HW packed fp8-e4m3 convert (RNE): bytes [7:0]=fp8(a), [15:8]=fp8(b)
__device__ __forceinline__ u32 cvt2fp8(float a, float b) {
    u32 d;
    asm("v_cvt_pk_fp8_f32 %0, %1, %2" : "=v"(d) : "v"(a), "v"(b));
    return d;
}

// async global->LDS, 16B per lane. LDS dest = wave-uniform base + lane*16.
__device__ __forceinline__ void gld16(const void* g, void* l) {
    __builtin_amdgcn_global_load_lds(
        (const __attribute__((address_space(1))) unsigned int*)g,
        (__attribute__((address_space(3))) unsigned int*)l, 16, 0, 0);
}

// fp8 k-interleave within each 64-k group: k = s*32 + q*8 + j  ->  pos = q*16 + s*8 + j.
// Makes one lane's two BK=64 k-fragments a single aligned 16-B LDS read at 64-B row
// stride (m97-proven conflict class) instead of two stride-32 b64 reads (4-way).

// ---------------- fused transpose + convert of all six weights ----------------
// Wq..W1 -> bf16 [out][in]; W2 -> fp8 e4m3 scaled x64, k-interleaved.
__global__ __launch_bounds__(256) void transpose_all(
    const float* __restrict__ Wq, const float* __restrict__ Wk,
    const float* __restrict__ Wv, const float* __restrict__ Wo,
    const float* __restrict__ W1, const float* __restrict__ W2, u16* __restrict__ wqkvT,
    u16* __restrict__ woT, u16* __restrict__ w1T, u8* __restrict__ w2T8) {
    __shared__ float tile[32][33];
    int t = blockIdx.x;
    const float* in;
    u16* out = nullptr;
    int R, C;
    bool isf8 = false;
    if (t < 3072) {
        int m = t >> 10;
        t &= 1023;
        in = m == 0 ? Wq : (m == 1 ? Wk : Wv);
        out = wqkvT + m * 1048576;
        R = 1024; C = 1024;
    } else if (t < 4096) {
        t -= 3072; in = Wo; out = woT; R = 1024; C = 1024;
    } else if (t < 8192) {
        t -= 4096; in = W1; out = w1T; R = 1024; C = 4096;
    } else {
        t -= 8192; in = W2; R = 4096; C = 1024; isf8 = true;
    }
    int tilesX = C >> 5;
    int c0 = (t % tilesX) * 32, r0 = (t / tilesX) * 32;
    int tx = threadIdx.x, ty = threadIdx.y;
#pragma unroll
    for (int i = 0; i < 4; i++)
        tile[ty + i * 8][tx] = in[(size_t)(r0 + ty + i * 8) * C + c0 + tx];
    __syncthreads();
    if (isf8) {
        // k = r0+tx (r0 mult of 32, tx<32): pos = base + q*16 + s*8 + j
        int pos = (r0 & ~63) + (tx >> 3) * 16 + ((r0 >> 5) & 1) * 8 + (tx & 7);
        u32 p01 = cvt2fp8(tile[tx][ty] * 64.0f, tile[tx][ty + 8] * 64.0f);
        u32 p23 = cvt2fp8(tile[tx][ty + 16] * 64.0f, tile[tx][ty + 24] * 64.0f);
        w2T8[(size_t)(c0 + ty) * 4096 + pos] = (u8)p01;
        w2T8[(size_t)(c0 + ty + 8) * 4096 + pos] = (u8)(p01 >> 8);
        w2T8[(size_t)(c0 + ty + 16) * 4096 + pos] = (u8)p23;
        w2T8[(size_t)(c0 + ty + 24) * 4096 + pos] = (u8)(p23 >> 8);
    } else {
#pragma unroll
        for (int i = 0; i < 4; i++)
            out[(size_t)(c0 + ty + i * 8) * R + r0 + tx] = f2b(tile[tx][ty + i * 8]);
    }
}

// ---------------- LayerNorm: fp32 [4096][1024] -> bf16 [4096][1024] ----------------
__global__ __launch_bounds__(256) void ln_kernel(const float* __restrict__ x,
                                                 const float* __restrict__ g,
                                                 const float* __restrict__ b,
                                                 u16* __restrict__ out) {
    int row = blockIdx.x;
    int tid = threadIdx.x;
    const float* xr = x + (size_t)row * 1024;
    float4 v = ((const float4*)xr)[tid];
    float s = v.x + v.y + v.z + v.w;
    float s2 = v.x * v.x + v.y * v.y + v.z * v.z + v.w * v.w;
#pragma unroll
    for (int off = 32; off > 0; off >>= 1) {
        s += __shfl_xor(s, off);
        s2 += __shfl_xor(s2, off);
    }
    __shared__ float ps[4], ps2[4];
    int wid = tid >> 6;
    if ((tid & 63) == 0) { ps[wid] = s; ps2[wid] = s2; }
    __syncthreads();
    s = ps[0] + ps[1] + ps[2] + ps[3];
    s2 = ps2[0] + ps2[1] + ps2[2] + ps2[3];
    float mu = s * (1.0f / 1024.0f);
    float var = s2 * (1.0f / 1024.0f) - mu * mu;
    float rs = rsqrtf(var + 1e-5f);
    int c = tid * 4;
    ushort4 o;
    o.x = f2b((v.x - mu) * rs * g[c + 0] + b[c + 0]);
    o.y = f2b((v.y - mu) * rs * g[c + 1] + b[c + 1]);
    o.z = f2b((v.z - mu) * rs * g[c + 2] + b[c + 2]);
    o.w = f2b((v.w - mu) * rs * g[c + 3] + b[c + 3]);
    ((ushort4*)(out + (size_t)row * 1024))[tid] = o;
}

// ---------------- V transpose+permute: Vb [bh][2048][64] -> VbT [bh][64][2048'] --------
// kv permuted within each 32-block: pi(c) = (c&15)*2 + (c>>4); attention P-transform
// writes packed b32 pairs; PV contraction permutes both operands -> unchanged result.
__global__ __launch_bounds__(256) void vtrans_kernel(const u16* __restrict__ Vb,
                                                     u16* __restrict__ VbT) {
    __shared__ u16 t[64][66];
    const int tid = threadIdx.x;
    const int s0 = blockIdx.x * 64;
    const int bh = blockIdx.y;
    const u16* src = Vb + (size_t)bh * 2048 * 64;
    u16* dst = VbT + (size_t)bh * 64 * 2048;
#pragma unroll
    for (int p = 0; p < 2; p++) {
        int idx = p * 256 + tid;
        int r = idx >> 3, dc = (idx & 7) * 8;
        uint4 v = *(const uint4*)&src[(size_t)(s0 + r) * 64 + dc];
        const u16* pv = (const u16*)&v;
#pragma unroll
        for (int j = 0; j < 8; j++) t[r][dc + j] = pv[j];
    }
    __syncthreads();
    int d = tid >> 2, sc = (tid & 3) * 16;
    u16 buf[16];
#pragma unroll
    for (int m = 0; m < 16; m++) {
        int cp = sc + m;
        int blk = cp >> 5, c = cp & 31;
        int srcw = blk * 32 + (c >> 1) + (c & 1) * 16;  // pi^-1
        buf[m] = t[srcw][d];
    }
    *(uint4*)&dst[(size_t)d * 2048 + s0 + sc] = *(uint4*)&buf[0];
    *(uint4*)&dst[(size_t)d * 2048 + s0 + sc + 8] = *(uint4*)&buf[8];
}

// ---------------- bf16 MFMA GEMM 128x128 (QKV / W1-GELU) ----------------
#define EPI_QKV 0
#define EPI_RESID 1
#define EPI_GELU 2

__device__ __forceinline__ void gemm_stage(const u16* __restrict__ A,
                                           const u16* __restrict__ BT,
                                           u16 (&Asb)[128][32], u16 (&Bsb)[128][32],
                                           int m0, int n0, int K, int k0, int sr, int sdc,
                                           int wb) {
    gld16(&A[(size_t)(m0 + sr) * K + k0 + sdc], &Asb[0][0] + wb);
    gld16(&A[(size_t)(m0 + 64 + sr) * K + k0 + sdc], &Asb[0][0] + 2048 + wb);
    gld16(&BT[(size_t)(n0 + sr) * K + k0 + sdc], &Bsb[0][0] + wb);
    gld16(&BT[(size_t)(n0 + 64 + sr) * K + k0 + sdc], &Bsb[0][0] + 2048 + wb);
}

__device__ __forceinline__ void gemm_compute(const u16 (&Asb)[128][32],
                                             const u16 (&Bsb)[128][32], f32x4 (&acc)[4][4],
                                             int wm, int wn, int quad, int c15) {
    bf16x8 af[4], bfr[4];
#pragma unroll
    for (int i = 0; i < 4; i++) af[i] = *(const bf16x8*)&Asb[wm + i * 16 + c15][quad * 8];
#pragma unroll
    for (int j = 0; j < 4; j++) bfr[j] = *(const bf16x8*)&Bsb[wn + j * 16 + c15][quad * 8];
#pragma unroll
    for (int i = 0; i < 4; i++)
#pragma unroll
        for (int j = 0; j < 4; j++) acc[i][j] = MFMA16(af[i], bfr[j], acc[i][j]);
}

template <int EPI>
__global__ __launch_bounds__(256) void gemm_kernel(const u16* __restrict__ A,
                                                   const u16* __restrict__ BT,
                                                   const float* __restrict__ bias0,
                                                   const float* __restrict__ bias1,
                                                   const float* __restrict__ bias2,
                                                   void* __restrict__ outp,
                                                   const float* __restrict__ resid,
                                                   int N, int K) {
    __shared__ __align__(16) u16 As0[128][32], Bs0[128][32];
    __shared__ __align__(16) u16 As1[128][32], Bs1[128][32];
    const int tid = threadIdx.x;
    const int m0 = blockIdx.y * 128, n0 = blockIdx.x * 128;
    const int w = tid >> 6, lid = tid & 63, quad = lid >> 4, c15 = lid & 15;
    const int wm = (w >> 1) * 64, wn = (w & 1) * 64;
    const int sr = tid >> 2, sdc = (tid & 3) * 8;
    const int wb = (tid & 192) * 8;

    f32x4 acc[4][4] = {};

    gemm_stage(A, BT, As0, Bs0, m0, n0, K, 0, sr, sdc, wb);
    const int KT = K >> 5;  // even (32 or 128)
    for (int kt = 0; kt < KT; kt += 2) {
        __syncthreads();
        gemm_stage(A, BT, As1, Bs1, m0, n0, K, (kt + 1) << 5, sr, sdc, wb);
        gemm_compute(As0, Bs0, acc, wm, wn, quad, c15);
        __syncthreads();
        if (kt + 2 < KT) gemm_stage(A, BT, As0, Bs0, m0, n0, K, (kt + 2) << 5, sr, sdc, wb);
        gemm_compute(As1, Bs1, acc, wm, wn, quad, c15);
    }

    const int which = n0 >> 10;
    const float* bias = (EPI == EPI_QKV) ? (which == 0 ? bias0 : (which == 1 ? bias1 : bias2))
                                         : bias0;
    u16* qkv_dst = (u16*)outp + (size_t)which * 4194304;

    // hoisted k-interleave positions for the GELU->fp8 epilogue
    int posj[4];
    if (EPI == EPI_GELU) {
#pragma unroll
        for (int j = 0; j < 4; j++) {
            int gc = n0 + wn + j * 16 + c15;
            int g = gc & 63;
            posj[j] = (gc & ~63) + ((g >> 3) & 3) * 16 + ((g >> 5) & 1) * 8 + (g & 7);
        }
    }

#pragma unroll
    for (int i = 0; i < 4; i++) {
#pragma unroll
        for (int j = 0; j < 4; j++) {
            if (EPI == EPI_GELU) {
                int gc = n0 + wn + j * 16 + c15;
                float vv[4];
#pragma unroll
                for (int r = 0; r < 4; r++) {
                    // gelu(v) = v * sigmoid(2u), u = v*(c1 + c2 v^2)  [tanh form]
                    float v = acc[i][j][r] + bias[gc];
                    float t = v * v;
                    float u2 = v * (1.59576912f + 0.07135482f * t);
                    float e = __expf(u2);
                    float q = __frcp_rn(e + 1.0f);
                    vv[r] = v - v * q;
                }
                u32 p01 = cvt2fp8(vv[0], vv[1]);
                u32 p23 = cvt2fp8(vv[2], vv[3]);
                int gr = m0 + wm + i * 16 + quad * 4;
                u8* dst = (u8*)outp + (size_t)gr * N + posj[j];
                dst[0] = (u8)p01;
                dst[N] = (u8)(p01 >> 8);
                dst[2 * N] = (u8)p23;
                dst[3 * N] = (u8)(p23 >> 8);
            } else {
#pragma unroll
                for (int r = 0; r < 4; r++) {
                    int gr = m0 + wm + i * 16 + quad * 4 + r;
                    int gc = n0 + wn + j * 16 + c15;
                    if (EPI == EPI_QKV) {
                        int lc = gc & 1023;
                        float v = acc[i][j][r] + bias[lc];
                        int bb = gr >> 11, ss = gr & 2047, hh = lc >> 6, dd = lc & 63;
                        qkv_dst[((size_t)((bb * 16 + hh) * 2048 + ss)) * 64 + dd] = f2b(v);
                    } else {  // EPI_RESID
                        float v = acc[i][j][r] + bias[gc];
                        ((float*)outp)[(size_t)gr * N + gc] =
                            resid[(size_t)gr * N + gc] + v;
                    }
                }
            }
        }
    }
}

// ---------------- bf16 MFMA GEMM 128x64 (O-proj): grid 512 = 2 blocks/CU ----------------
__global__ __launch_bounds__(256) void gemm64_kernel(const u16* __restrict__ A,
                                                     const u16* __restrict__ BT,
                                                     const float* __restrict__ bias,
                                                     float* __restrict__ outp,
                                                     const float* __restrict__ resid,
                                                     int N, int K) {
    __shared__ __align__(16) u16 As0[128][32], Bs0[64][32];
    __shared__ __align__(16) u16 As1[128][32], Bs1[64][32];
    const int tid = threadIdx.x;
    const int m0 = blockIdx.y * 128, n0 = blockIdx.x * 64;
    const int w = tid >> 6, lid = tid & 63, quad = lid >> 4, c15 = lid & 15;
    const int wm = (w >> 1) * 64, wn = (w & 1) * 32;
    const int sr = tid >> 2, sdc = (tid & 3) * 8;
    const int wb = (tid & 192) * 8;

    f32x4 acc[4][2] = {};

    auto stage = [&](u16 (&Asb)[128][32], u16 (&Bsb)[64][32], int k0) {
        gld16(&A[(size_t)(m0 + sr) * K + k0 + sdc], &Asb[0][0] + wb);
        gld16(&A[(size_t)(m0 + 64 + sr) * K + k0 + sdc], &Asb[0][0] + 2048 + wb);
        gld16(&BT[(size_t)(n0 + sr) * K + k0 + sdc], &Bsb[0][0] + wb);
    };
    auto compute = [&](const u16 (&Asb)[128][32], const u16 (&Bsb)[64][32]) {
        bf16x8 af[4], bfr[2];
#pragma unroll
        for (int i = 0; i < 4; i++) af[i] = *(const bf16x8*)&Asb[wm + i * 16 + c15][quad * 8];
#pragma unroll
        for (int j = 0; j < 2; j++) bfr[j] = *(const bf16x8*)&Bsb[wn + j * 16 + c15][quad * 8];
#pragma unroll
        for (int i = 0; i < 4; i++)
#pragma unroll
            for (int j = 0; j < 2; j++) acc[i][j] = MFMA16(af[i], bfr[j], acc[i][j]);
    };

    stage(As0, Bs0, 0);
    const int KT = K >> 5;
    for (int kt = 0; kt < KT; kt += 2) {
        __syncthreads();
        stage(As1, Bs1, (kt + 1) << 5);
        compute(As0, Bs0);
        __syncthreads();
        if (kt + 2 < KT) stage(As0, Bs0, (kt + 2) << 5);
        compute(As1, Bs1);
    }

#pragma unroll
    for (int i = 0; i < 4; i++) {
#pragma unroll
        for (int j = 0; j < 2; j++) {
#pragma unroll
            for (int r = 0; r < 4; r++) {
                int gr = m0 + wm + i * 16 + quad * 4 + r;
                int gc = n0 + wn + j * 16 + c15;
                float v = acc[i][j][r] + bias[gc];
                outp[(size_t)gr * N + gc] = resid[(size_t)gr * N + gc] + v;
            }
        }
    }
}

// ---------------- fp8 MFMA GEMM (W2): out = resid + mid8 @ w2T8^T /64 + bias --------
// Tile 128x64, BK=64 (k-interleaved operands -> b128 frag reads at 64-B row stride),
// grid 512 = 2 blocks/CU, dbuf-2 + __syncthreads.
__global__ __launch_bounds__(256) void gemm_fp8_kernel(const u8* __restrict__ A,
                                                       const u8* __restrict__ BT,
                                                       const float* __restrict__ bias,
                                                       float* __restrict__ outp,
                                                       const float* __restrict__ resid,
                                                       int N, int K) {
    __shared__ __align__(16) u8 As0[128][64], Bs0[64][64];
    __shared__ __align__(16) u8 As1[128][64], Bs1[64][64];
    const int tid = threadIdx.x;
    const int m0 = blockIdx.y * 128, n0 = blockIdx.x * 64;
    const int w = tid >> 6, lid = tid & 63, quad = lid >> 4, c15 = lid & 15;
    const int wm = (w >> 1) * 64, wn = (w & 1) * 32;
    const int sr = tid >> 2, sdc = (tid & 3) * 16;
    const int wbB = (tid & 192) * 16;  // wave's 1024-B LDS chunk (bytes)

    f32x4 acc[4][2] = {};

    auto stage = [&](u8 (&Asb)[128][64], u8 (&Bsb)[64][64], int k0) {
        gld16(&A[(size_t)(m0 + sr) * K + k0 + sdc], &Asb[0][0] + wbB);
        gld16(&A[(size_t)(m0 + 64 + sr) * K + k0 + sdc], &Asb[0][0] + 4096 + wbB);
        gld16(&BT[(size_t)(n0 + sr) * K + k0 + sdc], &Bsb[0][0] + wbB);
    };
    auto compute = [&](const u8 (&Asb)[128][64], const u8 (&Bsb)[64][64]) {
        i64x2 af[4], bfr[2];
#pragma unroll
        for (int i = 0; i < 4; i++)
            af[i] = *(const i64x2*)&Asb[wm + i * 16 + c15][quad * 16];
#pragma unroll
        for (int j = 0; j < 2; j++)
            bfr[j] = *(const i64x2*)&Bsb[wn + j * 16 + c15][quad * 16];
#pragma unroll
        for (int s = 0; s < 2; s++)
#pragma unroll
            for (int i = 0; i < 4; i++)
#pragma unroll
                for (int j = 0; j < 2; j++)
                    acc[i][j] = MFMA8(af[i][s], bfr[j][s], acc[i][j]);
    };

    stage(As0, Bs0, 0);
    const int KT = K >> 6;  // 64
    for (int kt = 0; kt < KT; kt += 2) {
        __syncthreads();
        stage(As1, Bs1, (kt + 1) << 6);
        compute(As0, Bs0);
        __syncthreads();
        if (kt + 2 < KT) stage(As0, Bs0, (kt + 2) << 6);
        compute(As1, Bs1);
    }

#pragma unroll
    for (int i = 0; i < 4; i++) {
#pragma unroll
        for (int j = 0; j < 2; j++) {
#pragma unroll
            for (int r = 0; r < 4; r++) {
                int gr = m0 + wm + i * 16 + quad * 4 + r;
                int gc = n0 + wn + j * 16 + c15;
                float v = acc[i][j][r] * (1.0f / 64.0f) + bias[gc];  // w2 scaled x64
                outp[(size_t)gr * N + gc] = resid[(size_t)gr * N + gc] + v;
            }
        }
    }
}

// ---------------- causal flash attention: 64-q blocks, longest-first ----------------
// grid (32 bh, 32 q-tiles), qt = 31-by. Block = 4 waves x 16 q rows; kv-step 64;
// dbuf-2 K/V via gld16; no online max (LN'd inputs: scores O(2), exp safe).
__device__ __forceinline__ void attn_step(const u16 (&KB)[2][64][32],
                                          const u16 (&VB)[2][64][32],
                                          u16 (&Psw)[2][16][48], const bf16x8 (&aq)[2],
                                          f32x4 (&o)[4], float (&lsum)[4], int kv0,
                                          int qr0, int quad, int c15) {
    bf16x8 bk[4][2];
#pragma unroll
    for (int nf = 0; nf < 4; nf++)
#pragma unroll
        for (int kd = 0; kd < 2; kd++)
            bk[nf][kd] = *(const bf16x8*)&KB[kd][nf * 16 + c15][quad * 8];
    f32x4 sf[4];
#pragma unroll
    for (int nf = 0; nf < 4; nf++) {
        f32x4 s = {};
        s = MFMA16(aq[0], bk[nf][0], s);
        s = MFMA16(aq[1], bk[nf][1], s);
        sf[nf] = s;
    }
    const bool domask = (kv0 + 63 > qr0);
    if (domask) {
#pragma unroll
        for (int r = 0; r < 4; r++) {
            int rowg = qr0 + quad * 4 + r;
#pragma unroll
            for (int nf = 0; nf < 4; nf++) {
                float p = (kv0 + nf * 16 + c15 <= rowg) ? __expf(sf[nf][r] * 0.125f) : 0.0f;
                sf[nf][r] = p;
                lsum[r] += p;
            }
        }
    } else {
#pragma unroll
        for (int r = 0; r < 4; r++)
#pragma unroll
            for (int nf = 0; nf < 4; nf++) {
                float p = __expf(sf[nf][r] * 0.125f);
                sf[nf][r] = p;
                lsum[r] += p;
            }
    }
    // P: C-layout -> A-layout via LDS, kv-permuted to pack b32 writes
#pragma unroll
    for (int ks = 0; ks < 2; ks++)
#pragma unroll
        for (int r = 0; r < 4; r++) {
            u32 pk = (u32)f2b(sf[2 * ks][r]) | ((u32)f2b(sf[2 * ks + 1][r]) << 16);
            *(u32*)&Psw[ks][quad * 4 + r][2 * c15] = pk;
        }
    asm volatile("s_waitcnt lgkmcnt(0)" ::: "memory");  // same-wave Ps write->read
    bf16x8 ap[2];
#pragma unroll
    for (int ks = 0; ks < 2; ks++) ap[ks] = *(const bf16x8*)&Psw[ks][c15][quad * 8];
#pragma unroll
    for (int df = 0; df < 4; df++) {
        bf16x8 bv0 = *(const bf16x8*)&VB[0][df * 16 + c15][quad * 8];
        bf16x8 bv1 = *(const bf16x8*)&VB[1][df * 16 + c15][quad * 8];
        o[df] = MFMA16(ap[0], bv0, o[df]);
        o[df] = MFMA16(ap[1], bv1, o[df]);
    }
}

__global__ __launch_bounds__(256) void attn_kernel(const u16* __restrict__ Q,
                                                   const u16* __restrict__ Kb,
                                                   const u16* __restrict__ VbT,
                                                   u16* __restrict__ attO) {
    __shared__ __align__(16) u16 Ks[2][2][64][32];  // [buf][d-half][kv][d32]
    __shared__ __align__(16) u16 Vs[2][2][64][32];  // [buf][kv-half][d][kv32]
    __shared__ __align__(16) u16 Ps[4][2][16][48];

    const int tid = threadIdx.x;
    const int bh = blockIdx.x;
    const int qt = 31 - blockIdx.y;  // longest q-tiles dispatched first
    const int q0 = qt * 64;
    const size_t base = (size_t)bh * 2048 * 64;
    const u16* Qp = Q + base;
    const u16* Kp = Kb + base;
    const u16* Vp = VbT + (size_t)bh * 64 * 2048;
    const int w = tid >> 6, lane = tid & 63, quad = lane >> 4, c15 = lane & 15;
    const int qr0 = q0 + w * 16;
    const int sr = tid >> 2, sdc = (tid & 3) * 8;
    const int wb = (tid & 192) * 8;
    const int bb = bh >> 4, hh = bh & 15;

#define ATTN_STAGE(bi, kvo)                                                             \
    do {                                                                                \
        gld16(&Kp[(size_t)((kvo) + sr) * 64 + sdc], &Ks[bi][0][0][0] + wb);             \
        gld16(&Kp[(size_t)((kvo) + sr) * 64 + 32 + sdc], &Ks[bi][0][0][0] + 2048 + wb); \
        gld16(&Vp[(size_t)sr * 2048 + (kvo) + sdc], &Vs[bi][0][0][0] + wb);             \
        gld16(&Vp[(size_t)sr * 2048 + (kvo) + 32 + sdc], &Vs[bi][0][0][0] + 2048 + wb); \
    } while (0)

    bf16x8 aq[2];
#pragma unroll
    for (int ks = 0; ks < 2; ks++)
        aq[ks] = *(const bf16x8*)&Qp[(size_t)(qr0 + c15) * 64 + ks * 32 + quad * 8];

    f32x4 o[4] = {};
    float lsum[4] = {};
    const int steps = qt + 1;

    ATTN_STAGE(0, 0);
    for (int s = 0; s < steps; s++) {
        __syncthreads();
        if (s + 1 < steps) ATTN_STAGE((s + 1) & 1, (s + 1) << 6);
        attn_step(Ks[s & 1], Vs[s & 1], Ps[w], aq, o, lsum, s << 6, qr0, quad, c15);
    }

#pragma unroll
    for (int r = 0; r < 4; r++) {
        float l = lsum[r];
#pragma unroll
        for (int off = 1; off < 16; off <<= 1) l += __shfl_xor(l, off);
        float inv = 1.0f / l;
        int sg = qr0 + quad * 4 + r;
        size_t rowoff = ((size_t)(bb * 2048 + sg)) * 1024 + hh * 64;
#pragma unroll
        for (int df = 0; df < 4; df++) attO[rowoff + df * 16 + c15] = f2b(o[df][r] * inv);
    }
#undef ATTN_STAGE
}

// ---------------- launcher ----------------
extern "C" void kernel_launch(void* const* d_in, const int* in_sizes, int n_in,
                              void* d_out, int out_size, void* d_ws, size_t ws_size,
                              hipStream_t stream) {
    const float* x = (const float*)d_in[0];
    const float* ln1g = (const float*)d_in[1];
    const float* ln1b = (const float*)d_in[2];
    const float* Wq = (const float*)d_in[3];
    const float* bq = (const float*)d_in[4];
    const float* Wk = (const float*)d_in[5];
    const float* bk = (const float*)d_in[6];
    const float* Wv = (const float*)d_in[7];
    const float* bv = (const float*)d_in[8];
    const float* Wo = (const float*)d_in[9];
    const float* bo = (const float*)d_in[10];
    const float* ln2g = (const float*)d_in[11];
    const float* ln2b = (const float*)d_in[12];
    const float* W1 = (const float*)d_in[13];
    const float* b1 = (const float*)d_in[14];
    const float* W2 = (const float*)d_in[15];
    const float* b2 = (const float*)d_in[16];
    float* out = (float*)d_out;

    char* ws = (char*)d_ws;
    u16* wqkvT = (u16*)(ws + 0);              // [3072][1024] bf16, 6 MB
    u16* woT = (u16*)(ws + 6291456);          // [1024][1024], 2 MB
    u16* w1T = (u16*)(ws + 8388608);          // [4096][1024], 8 MB
    u8* w2T8 = (u8*)(ws + 16777216);          // [1024][4096] fp8 x64, k-interleaved, 4 MB
    u16* h = (u16*)(ws + 25165824);           // [4096][1024] bf16, 8 MB
    float* x1 = (float*)(ws + 33554432);      // [4096][1024] fp32, 16 MB
    u16* Qb = (u16*)(ws + 50331648);          // [32 bh][2048][64], 8 MB
    u16* Kb = (u16*)(ws + 58720256);          // 8 MB
    u16* Vb = (u16*)(ws + 67108864);          // 8 MB (later reused as aO)
    u16* VbT = (u16*)(ws + 75497472);         // [32 bh][64][2048'] permuted, 8 MB
    u16* aO = Vb;
    u8* mid8 = (u8*)(ws + 50331648);          // [4096][4096] fp8 k-interleaved, 16 MB

    transpose_all<<<12288, dim3(32, 8), 0, stream>>>(Wq, Wk, Wv, Wo, W1, W2, wqkvT, woT,
                                                     w1T, w2T8);

    ln_kernel<<<4096, 256, 0, stream>>>(x, ln1g, ln1b, h);

    gemm_kernel<EPI_QKV><<<dim3(24, 32), 256, 0, stream>>>(h, wqkvT, bq, bk, bv, Qb, nullptr,
                                                           3072, 1024);

    vtrans_kernel<<<dim3(32, 32), 256, 0, stream>>>(Vb, VbT);

    attn_kernel<<<dim3(32, 32), 256, 0, stream>>>(Qb, Kb, VbT, aO);

    gemm64_kernel<<<dim3(16, 32), 256, 0, stream>>>(aO, woT, bo, x1, x, 1024, 1024);

    ln_kernel<<<4096, 256, 0, stream>>>(x1, ln2g, ln2b, h);

    gemm_kernel<EPI_GELU><<<dim3(32, 32), 256, 0, stream>>>(h, w1T, b1, nullptr, nullptr, mid8,
                                                            nullptr, 4096, 1024);
    gemm_fp8_kernel<<<dim3(16, 32), 256, 0, stream>>>(mid8, w2T8, b2, out, x1, 1024, 4096);
}

// Round 9
// 312.498 us; speedup vs baseline: 1.0880x; 1.0339x over previous
//
#include <hip/hip_runtime.h>
#include <hip/hip_bf16.h>
#include <hip/hip_fp8.h>
#include <math.h>

typedef unsigned short u16;
typedef unsigned char u8;
typedef unsigned int u32;
typedef long i64;
typedef __bf16 bf16x8 __attribute__((ext_vector_type(8)));
typedef float f32x4 __attribute__((ext_vector_type(4)));
typedef i64 i64x2 __attribute__((ext_vector_type(2)));

#define MFMA16(a, b, c) __builtin_amdgcn_mfma_f32_16x16x32_bf16(a, b, c, 0, 0, 0)
#define MFMA8(a, b, c) __builtin_amdgcn_mfma_f32_16x16x32_fp8_fp8(a, b, c, 0, 0, 0)

__device__ __forceinline__ u16 f2b(float f) {
    __bf16 h = (__bf16)f;
    return __builtin_bit_cast(u16, h);
}

// HW packed fp8-e4m3 convert (RNE): bytes [7:0]=fp8(a), [15:8]=fp8(b)
__device__ __forceinline__ u32 cvt2fp8(float a, float b) {
    u32 d;
    asm("v_cvt_pk_fp8_f32 %0, %1, %2" : "=v"(d) : "v"(a), "v"(b));
    return d;
}

// async global->LDS, 16B per lane. LDS dest = wave-uniform base + lane*16.
__device__ __forceinline__ void gld16(const void* g, void* l) {
    __builtin_amdgcn_global_load_lds(
        (const __attribute__((address_space(1))) unsigned int*)g,
        (__attribute__((address_space(3))) unsigned int*)l, 16, 0, 0);
}

// fp8 k-interleave within each 64-k group: k = s*32 + q*8 + j  ->  pos = q*16 + s*8 + j.
// One lane's two BK=64 k-fragments become a single aligned 16-B LDS read at 64-B row
// stride (m97-proven conflict class).
__device__ __forceinline__ int kpos(int k) {
    return (k & ~63) + ((k >> 3) & 3) * 16 + ((k >> 5) & 1) * 8 + (k & 7);
}

// ---------------- fused transpose + convert of all six weights ----------------
// Wq..Wo -> bf16 [out][in]; W1 -> fp8 x32 k-interleaved; W2 -> fp8 x64 k-interleaved.
__global__ __launch_bounds__(256) void transpose_all(
    const float* __restrict__ Wq, const float* __restrict__ Wk,
    const float* __restrict__ Wv, const float* __restrict__ Wo,
    const float* __restrict__ W1, const float* __restrict__ W2, u16* __restrict__ wqkvT,
    u16* __restrict__ woT, u8* __restrict__ w1T8, u8* __restrict__ w2T8) {
    __shared__ float tile[32][33];
    int t = blockIdx.x;
    const float* in;
    u16* out = nullptr;
    u8* out8 = nullptr;
    int R, C;
    float sc = 1.0f;
    if (t < 3072) {
        int m = t >> 10;
        t &= 1023;
        in = m == 0 ? Wq : (m == 1 ? Wk : Wv);
        out = wqkvT + m * 1048576;
        R = 1024; C = 1024;
    } else if (t < 4096) {
        t -= 3072; in = Wo; out = woT; R = 1024; C = 1024;
    } else if (t < 8192) {
        t -= 4096; in = W1; out8 = w1T8; R = 1024; C = 4096; sc = 32.0f;
    } else {
        t -= 8192; in = W2; out8 = w2T8; R = 4096; C = 1024; sc = 64.0f;
    }
    int tilesX = C >> 5;
    int c0 = (t % tilesX) * 32, r0 = (t / tilesX) * 32;
    int tx = threadIdx.x, ty = threadIdx.y;
#pragma unroll
    for (int i = 0; i < 4; i++)
        tile[ty + i * 8][tx] = in[(size_t)(r0 + ty + i * 8) * C + c0 + tx];
    __syncthreads();
    if (out8) {
        // k = r0+tx: interleaved byte position within the [out-dim][R] fp8 matrix
        int pos = (r0 & ~63) + (tx >> 3) * 16 + ((r0 >> 5) & 1) * 8 + (tx & 7);
        u32 p01 = cvt2fp8(tile[tx][ty] * sc, tile[tx][ty + 8] * sc);
        u32 p23 = cvt2fp8(tile[tx][ty + 16] * sc, tile[tx][ty + 24] * sc);
        out8[(size_t)(c0 + ty) * R + pos] = (u8)p01;
        out8[(size_t)(c0 + ty + 8) * R + pos] = (u8)(p01 >> 8);
        out8[(size_t)(c0 + ty + 16) * R + pos] = (u8)p23;
        out8[(size_t)(c0 + ty + 24) * R + pos] = (u8)(p23 >> 8);
    } else {
#pragma unroll
        for (int i = 0; i < 4; i++)
            out[(size_t)(c0 + ty + i * 8) * R + r0 + tx] = f2b(tile[tx][ty + i * 8]);
    }
}

// ---------------- LayerNorm: fp32 [4096][1024] -> bf16 or k-interleaved fp8 ----------
template <int F8>
__global__ __launch_bounds__(256) void ln_kernel(const float* __restrict__ x,
                                                 const float* __restrict__ g,
                                                 const float* __restrict__ b,
                                                 void* __restrict__ outp) {
    int row = blockIdx.x;
    int tid = threadIdx.x;
    const float* xr = x + (size_t)row * 1024;
    float4 v = ((const float4*)xr)[tid];
    float s = v.x + v.y + v.z + v.w;
    float s2 = v.x * v.x + v.y * v.y + v.z * v.z + v.w * v.w;
#pragma unroll
    for (int off = 32; off > 0; off >>= 1) {
        s += __shfl_xor(s, off);
        s2 += __shfl_xor(s2, off);
    }
    __shared__ float ps[4], ps2[4];
    int wid = tid >> 6;
    if ((tid & 63) == 0) { ps[wid] = s; ps2[wid] = s2; }
    __syncthreads();
    s = ps[0] + ps[1] + ps[2] + ps[3];
    s2 = ps2[0] + ps2[1] + ps2[2] + ps2[3];
    float mu = s * (1.0f / 1024.0f);
    float var = s2 * (1.0f / 1024.0f) - mu * mu;
    float rs = rsqrtf(var + 1e-5f);
    int c = tid * 4;
    float o0 = (v.x - mu) * rs * g[c + 0] + b[c + 0];
    float o1 = (v.y - mu) * rs * g[c + 1] + b[c + 1];
    float o2 = (v.z - mu) * rs * g[c + 2] + b[c + 2];
    float o3 = (v.w - mu) * rs * g[c + 3] + b[c + 3];
    if (F8) {
        // 4 consecutive channels (c%4==0) share the interleave group: one u32 store
        u32 pk = (cvt2fp8(o0, o1) & 0xffffu) | (cvt2fp8(o2, o3) << 16);
        int pos = kpos(c);
        *(u32*)((u8*)outp + (size_t)row * 1024 + pos) = pk;
    } else {
        ushort4 o;
        o.x = f2b(o0); o.y = f2b(o1); o.z = f2b(o2); o.w = f2b(o3);
        ((ushort4*)((u16*)outp + (size_t)row * 1024))[tid] = o;
    }
}

// ---------------- V transpose+permute: Vb [bh][2048][64] -> VbT [bh][64][2048'] --------
// kv permuted within each 32-block: pi(c) = (c&15)*2 + (c>>4); attention P-transform
// writes packed b32 pairs; PV contraction permutes both operands -> unchanged result.
__global__ __launch_bounds__(256) void vtrans_kernel(const u16* __restrict__ Vb,
                                                     u16* __restrict__ VbT) {
    __shared__ u16 t[64][66];
    const int tid = threadIdx.x;
    const int s0 = blockIdx.x * 64;
    const int bh = blockIdx.y;
    const u16* src = Vb + (size_t)bh * 2048 * 64;
    u16* dst = VbT + (size_t)bh * 64 * 2048;
#pragma unroll
    for (int p = 0; p < 2; p++) {
        int idx = p * 256 + tid;
        int r = idx >> 3, dc = (idx & 7) * 8;
        uint4 v = *(const uint4*)&src[(size_t)(s0 + r) * 64 + dc];
        const u16* pv = (const u16*)&v;
#pragma unroll
        for (int j = 0; j < 8; j++) t[r][dc + j] = pv[j];
    }
    __syncthreads();
    int d = tid >> 2, sc = (tid & 3) * 16;
    u16 buf[16];
#pragma unroll
    for (int m = 0; m < 16; m++) {
        int cp = sc + m;
        int blk = cp >> 5, c = cp & 31;
        int srcw = blk * 32 + (c >> 1) + (c & 1) * 16;  // pi^-1
        buf[m] = t[srcw][d];
    }
    *(uint4*)&dst[(size_t)d * 2048 + s0 + sc] = *(uint4*)&buf[0];
    *(uint4*)&dst[(size_t)d * 2048 + s0 + sc + 8] = *(uint4*)&buf[8];
}

// ---------------- bf16 MFMA GEMM 128x128 (QKV) ----------------
#define EPI_QKV 0
#define EPI_RESID 1
#define EPI_GELU 2

__device__ __forceinline__ void gemm_stage(const u16* __restrict__ A,
                                           const u16* __restrict__ BT,
                                           u16 (&Asb)[128][32], u16 (&Bsb)[128][32],
                                           int m0, int n0, int K, int k0, int sr, int sdc,
                                           int wb) {
    gld16(&A[(size_t)(m0 + sr) * K + k0 + sdc], &Asb[0][0] + wb);
    gld16(&A[(size_t)(m0 + 64 + sr) * K + k0 + sdc], &Asb[0][0] + 2048 + wb);
    gld16(&BT[(size_t)(n0 + sr) * K + k0 + sdc], &Bsb[0][0] + wb);
    gld16(&BT[(size_t)(n0 + 64 + sr) * K + k0 + sdc], &Bsb[0][0] + 2048 + wb);
}

__device__ __forceinline__ void gemm_compute(const u16 (&Asb)[128][32],
                                             const u16 (&Bsb)[128][32], f32x4 (&acc)[4][4],
                                             int wm, int wn, int quad, int c15) {
    bf16x8 af[4], bfr[4];
#pragma unroll
    for (int i = 0; i < 4; i++) af[i] = *(const bf16x8*)&Asb[wm + i * 16 + c15][quad * 8];
#pragma unroll
    for (int j = 0; j < 4; j++) bfr[j] = *(const bf16x8*)&Bsb[wn + j * 16 + c15][quad * 8];
#pragma unroll
    for (int i = 0; i < 4; i++)
#pragma unroll
        for (int j = 0; j < 4; j++) acc[i][j] = MFMA16(af[i], bfr[j], acc[i][j]);
}

__global__ __launch_bounds__(256) void gemm_qkv_kernel(const u16* __restrict__ A,
                                                       const u16* __restrict__ BT,
                                                       const float* __restrict__ bias0,
                                                       const float* __restrict__ bias1,
                                                       const float* __restrict__ bias2,
                                                       u16* __restrict__ outp, int N, int K) {
    __shared__ __align__(16) u16 As0[128][32], Bs0[128][32];
    __shared__ __align__(16) u16 As1[128][32], Bs1[128][32];
    const int tid = threadIdx.x;
    const int m0 = blockIdx.y * 128, n0 = blockIdx.x * 128;
    const int w = tid >> 6, lid = tid & 63, quad = lid >> 4, c15 = lid & 15;
    const int wm = (w >> 1) * 64, wn = (w & 1) * 64;
    const int sr = tid >> 2, sdc = (tid & 3) * 8;
    const int wb = (tid & 192) * 8;

    f32x4 acc[4][4] = {};

    gemm_stage(A, BT, As0, Bs0, m0, n0, K, 0, sr, sdc, wb);
    const int KT = K >> 5;
    for (int kt = 0; kt < KT; kt += 2) {
        __syncthreads();
        gemm_stage(A, BT, As1, Bs1, m0, n0, K, (kt + 1) << 5, sr, sdc, wb);
        gemm_compute(As0, Bs0, acc, wm, wn, quad, c15);
        __syncthreads();
        if (kt + 2 < KT) gemm_stage(A, BT, As0, Bs0, m0, n0, K, (kt + 2) << 5, sr, sdc, wb);
        gemm_compute(As1, Bs1, acc, wm, wn, quad, c15);
    }

    const int which = n0 >> 10;
    const float* bias = which == 0 ? bias0 : (which == 1 ? bias1 : bias2);
    u16* qkv_dst = outp + (size_t)which * 4194304;

#pragma unroll
    for (int i = 0; i < 4; i++) {
#pragma unroll
        for (int j = 0; j < 4; j++) {
#pragma unroll
            for (int r = 0; r < 4; r++) {
                int gr = m0 + wm + i * 16 + quad * 4 + r;
                int gc = n0 + wn + j * 16 + c15;
                int lc = gc & 1023;
                float v = acc[i][j][r] + bias[lc];
                int bb = gr >> 11, ss = gr & 2047, hh = lc >> 6, dd = lc & 63;
                qkv_dst[((size_t)((bb * 16 + hh) * 2048 + ss)) * 64 + dd] = f2b(v);
            }
        }
    }
}

// ---------------- bf16 MFMA GEMM 128x64 (O-proj): grid 512 = 2 blocks/CU ----------------
__global__ __launch_bounds__(256) void gemm64_kernel(const u16* __restrict__ A,
                                                     const u16* __restrict__ BT,
                                                     const float* __restrict__ bias,
                                                     float* __restrict__ outp,
                                                     const float* __restrict__ resid,
                                                     int N, int K) {
    __shared__ __align__(16) u16 As0[128][32], Bs0[64][32];
    __shared__ __align__(16) u16 As1[128][32], Bs1[64][32];
    const int tid = threadIdx.x;
    const int m0 = blockIdx.y * 128, n0 = blockIdx.x * 64;
    const int w = tid >> 6, lid = tid & 63, quad = lid >> 4, c15 = lid & 15;
    const int wm = (w >> 1) * 64, wn = (w & 1) * 32;
    const int sr = tid >> 2, sdc = (tid & 3) * 8;
    const int wb = (tid & 192) * 8;

    f32x4 acc[4][2] = {};

    auto stage = [&](u16 (&Asb)[128][32], u16 (&Bsb)[64][32], int k0) {
        gld16(&A[(size_t)(m0 + sr) * K + k0 + sdc], &Asb[0][0] + wb);
        gld16(&A[(size_t)(m0 + 64 + sr) * K + k0 + sdc], &Asb[0][0] + 2048 + wb);
        gld16(&BT[(size_t)(n0 + sr) * K + k0 + sdc], &Bsb[0][0] + wb);
    };
    auto compute = [&](const u16 (&Asb)[128][32], const u16 (&Bsb)[64][32]) {
        bf16x8 af[4], bfr[2];
#pragma unroll
        for (int i = 0; i < 4; i++) af[i] = *(const bf16x8*)&Asb[wm + i * 16 + c15][quad * 8];
#pragma unroll
        for (int j = 0; j < 2; j++) bfr[j] = *(const bf16x8*)&Bsb[wn + j * 16 + c15][quad * 8];
#pragma unroll
        for (int i = 0; i < 4; i++)
#pragma unroll
            for (int j = 0; j < 2; j++) acc[i][j] = MFMA16(af[i], bfr[j], acc[i][j]);
    };

    stage(As0, Bs0, 0);
    const int KT = K >> 5;
    for (int kt = 0; kt < KT; kt += 2) {
        __syncthreads();
        stage(As1, Bs1, (kt + 1) << 5);
        compute(As0, Bs0);
        __syncthreads();
        if (kt + 2 < KT) stage(As0, Bs0, (kt + 2) << 5);
        compute(As1, Bs1);
    }

#pragma unroll
    for (int i = 0; i < 4; i++) {
#pragma unroll
        for (int j = 0; j < 2; j++) {
#pragma unroll
            for (int r = 0; r < 4; r++) {
                int gr = m0 + wm + i * 16 + quad * 4 + r;
                int gc = n0 + wn + j * 16 + c15;
                float v = acc[i][j][r] + bias[gc];
                outp[(size_t)gr * N + gc] = resid[(size_t)gr * N + gc] + v;
            }
        }
    }
}

// ---------------- fp8 MFMA GEMM (W1-GELU and W2): tile 128x64, BK=64 ----------------
// k-interleaved operands -> b128 frag reads at 64-B row stride; dbuf-2 + __syncthreads.
// EPI_GELU: out = fp8(gelu(acc*invsc + bias)), k-interleaved (for the W2 pass).
// EPI_RESID: out = resid + acc*invsc + bias (fp32).
template <int EPI>
__global__ __launch_bounds__(256) void gemm_fp8_kernel(const u8* __restrict__ A,
                                                       const u8* __restrict__ BT,
                                                       const float* __restrict__ bias,
                                                       void* __restrict__ outp,
                                                       const float* __restrict__ resid,
                                                       int N, int K, float invsc) {
    __shared__ __align__(16) u8 As0[128][64], Bs0[64][64];
    __shared__ __align__(16) u8 As1[128][64], Bs1[64][64];
    const int tid = threadIdx.x;
    const int m0 = blockIdx.y * 128, n0 = blockIdx.x * 64;
    const int w = tid >> 6, lid = tid & 63, quad = lid >> 4, c15 = lid & 15;
    const int wm = (w >> 1) * 64, wn = (w & 1) * 32;
    const int sr = tid >> 2, sdc = (tid & 3) * 16;
    const int wbB = (tid & 192) * 16;

    f32x4 acc[4][2] = {};

    auto stage = [&](u8 (&Asb)[128][64], u8 (&Bsb)[64][64], int k0) {
        gld16(&A[(size_t)(m0 + sr) * K + k0 + sdc], &Asb[0][0] + wbB);
        gld16(&A[(size_t)(m0 + 64 + sr) * K + k0 + sdc], &Asb[0][0] + 4096 + wbB);
        gld16(&BT[(size_t)(n0 + sr) * K + k0 + sdc], &Bsb[0][0] + wbB);
    };
    auto compute = [&](const u8 (&Asb)[128][64], const u8 (&Bsb)[64][64]) {
        i64x2 af[4], bfr[2];
#pragma unroll
        for (int i = 0; i < 4; i++)
            af[i] = *(const i64x2*)&Asb[wm + i * 16 + c15][quad * 16];
#pragma unroll
        for (int j = 0; j < 2; j++)
            bfr[j] = *(const i64x2*)&Bsb[wn + j * 16 + c15][quad * 16];
#pragma unroll
        for (int s = 0; s < 2; s++)
#pragma unroll
            for (int i = 0; i < 4; i++)
#pragma unroll
                for (int j = 0; j < 2; j++)
                    acc[i][j] = MFMA8(af[i][s], bfr[j][s], acc[i][j]);
    };

    stage(As0, Bs0, 0);
    const int KT = K >> 6;
    for (int kt = 0; kt < KT; kt += 2) {
        __syncthreads();
        stage(As1, Bs1, (kt + 1) << 6);
        compute(As0, Bs0);
        __syncthreads();
        if (kt + 2 < KT) stage(As0, Bs0, (kt + 2) << 6);
        compute(As1, Bs1);
    }

    int posj[2];
    if (EPI == EPI_GELU) {
#pragma unroll
        for (int j = 0; j < 2; j++) posj[j] = kpos(n0 + wn + j * 16 + c15);
    }

#pragma unroll
    for (int i = 0; i < 4; i++) {
#pragma unroll
        for (int j = 0; j < 2; j++) {
            int gc = n0 + wn + j * 16 + c15;
            if (EPI == EPI_GELU) {
                float vv[4];
#pragma unroll
                for (int r = 0; r < 4; r++) {
                    // gelu(v) = v * sigmoid(2u), u = v*(c1 + c2 v^2)  [tanh form]
                    float v = acc[i][j][r] * invsc + bias[gc];
                    float t = v * v;
                    float u2 = v * (1.59576912f + 0.07135482f * t);
                    float e = __expf(u2);
                    float q = __frcp_rn(e + 1.0f);
                    vv[r] = v - v * q;
                }
                u32 p01 = cvt2fp8(vv[0], vv[1]);
                u32 p23 = cvt2fp8(vv[2], vv[3]);
                int gr = m0 + wm + i * 16 + quad * 4;
                u8* dst = (u8*)outp + (size_t)gr * N + posj[j];
                dst[0] = (u8)p01;
                dst[N] = (u8)(p01 >> 8);
                dst[2 * N] = (u8)p23;
                dst[3 * N] = (u8)(p23 >> 8);
            } else {
#pragma unroll
                for (int r = 0; r < 4; r++) {
                    int gr = m0 + wm + i * 16 + quad * 4 + r;
                    float v = acc[i][j][r] * invsc + bias[gc];
                    ((float*)outp)[(size_t)gr * N + gc] = resid[(size_t)gr * N + gc] + v;
                }
            }
        }
    }
}

// ---------------- causal flash attention: 64-q blocks, longest-first ----------------
// grid (32 bh, 32 q-tiles), qt = 31-by. Block = 4 waves x 16 q rows; kv-step 64;
// dbuf-2 K/V via gld16; no online max (LN'd inputs: scores O(2), exp safe).
__device__ __forceinline__ void attn_step(const u16 (&KB)[2][64][32],
                                          const u16 (&VB)[2][64][32],
                                          u16 (&Psw)[2][16][48], const bf16x8 (&aq)[2],
                                          f32x4 (&o)[4], float (&lsum)[4], int kv0,
                                          int qr0, int quad, int c15) {
    bf16x8 bk[4][2];
#pragma unroll
    for (int nf = 0; nf < 4; nf++)
#pragma unroll
        for (int kd = 0; kd < 2; kd++)
            bk[nf][kd] = *(const bf16x8*)&KB[kd][nf * 16 + c15][quad * 8];
    f32x4 sf[4];
#pragma unroll
    for (int nf = 0; nf < 4; nf++) {
        f32x4 s = {};
        s = MFMA16(aq[0], bk[nf][0], s);
        s = MFMA16(aq[1], bk[nf][1], s);
        sf[nf] = s;
    }
    const bool domask = (kv0 + 63 > qr0);
    if (domask) {
#pragma unroll
        for (int r = 0; r < 4; r++) {
            int rowg = qr0 + quad * 4 + r;
#pragma unroll
            for (int nf = 0; nf < 4; nf++) {
                float p = (kv0 + nf * 16 + c15 <= rowg) ? __expf(sf[nf][r] * 0.125f) : 0.0f;
                sf[nf][r] = p;
                lsum[r] += p;
            }
        }
    } else {
#pragma unroll
        for (int r = 0; r < 4; r++)
#pragma unroll
            for (int nf = 0; nf < 4; nf++) {
                float p = __expf(sf[nf][r] * 0.125f);
                sf[nf][r] = p;
                lsum[r] += p;
            }
    }
    // P: C-layout -> A-layout via LDS, kv-permuted to pack b32 writes
#pragma unroll
    for (int ks = 0; ks < 2; ks++)
#pragma unroll
        for (int r = 0; r < 4; r++) {
            u32 pk = (u32)f2b(sf[2 * ks][r]) | ((u32)f2b(sf[2 * ks + 1][r]) << 16);
            *(u32*)&Psw[ks][quad * 4 + r][2 * c15] = pk;
        }
    asm volatile("s_waitcnt lgkmcnt(0)" ::: "memory");  // same-wave Ps write->read
    bf16x8 ap[2];
#pragma unroll
    for (int ks = 0; ks < 2; ks++) ap[ks] = *(const bf16x8*)&Psw[ks][c15][quad * 8];
#pragma unroll
    for (int df = 0; df < 4; df++) {
        bf16x8 bv0 = *(const bf16x8*)&VB[0][df * 16 + c15][quad * 8];
        bf16x8 bv1 = *(const bf16x8*)&VB[1][df * 16 + c15][quad * 8];
        o[df] = MFMA16(ap[0], bv0, o[df]);
        o[df] = MFMA16(ap[1], bv1, o[df]);
    }
}

__global__ __launch_bounds__(256) void attn_kernel(const u16* __restrict__ Q,
                                                   const u16* __restrict__ Kb,
                                                   const u16* __restrict__ VbT,
                                                   u16* __restrict__ attO) {
    __shared__ __align__(16) u16 Ks[2][2][64][32];  // [buf][d-half][kv][d32]
    __shared__ __align__(16) u16 Vs[2][2][64][32];  // [buf][kv-half][d][kv32]
    __shared__ __align__(16) u16 Ps[4][2][16][48];

    const int tid = threadIdx.x;
    const int bh = blockIdx.x;
    const int qt = 31 - blockIdx.y;  // longest q-tiles dispatched first
    const int q0 = qt * 64;
    const size_t base = (size_t)bh * 2048 * 64;
    const u16* Qp = Q + base;
    const u16* Kp = Kb + base;
    const u16* Vp = VbT + (size_t)bh * 64 * 2048;
    const int w = tid >> 6, lane = tid & 63, quad = lane >> 4, c15 = lane & 15;
    const int qr0 = q0 + w * 16;
    const int sr = tid >> 2, sdc = (tid & 3) * 8;
    const int wb = (tid & 192) * 8;
    const int bb = bh >> 4, hh = bh & 15;

#define ATTN_STAGE(bi, kvo)                                                             \
    do {                                                                                \
        gld16(&Kp[(size_t)((kvo) + sr) * 64 + sdc], &Ks[bi][0][0][0] + wb);             \
        gld16(&Kp[(size_t)((kvo) + sr) * 64 + 32 + sdc], &Ks[bi][0][0][0] + 2048 + wb); \
        gld16(&Vp[(size_t)sr * 2048 + (kvo) + sdc], &Vs[bi][0][0][0] + wb);             \
        gld16(&Vp[(size_t)sr * 2048 + (kvo) + 32 + sdc], &Vs[bi][0][0][0] + 2048 + wb); \
    } while (0)

    bf16x8 aq[2];
#pragma unroll
    for (int ks = 0; ks < 2; ks++)
        aq[ks] = *(const bf16x8*)&Qp[(size_t)(qr0 + c15) * 64 + ks * 32 + quad * 8];

    f32x4 o[4] = {};
    float lsum[4] = {};
    const int steps = qt + 1;

    ATTN_STAGE(0, 0);
    for (int s = 0; s < steps; s++) {
        __syncthreads();
        if (s + 1 < steps) ATTN_STAGE((s + 1) & 1, (s + 1) << 6);
        attn_step(Ks[s & 1], Vs[s & 1], Ps[w], aq, o, lsum, s << 6, qr0, quad, c15);
    }

#pragma unroll
    for (int r = 0; r < 4; r++) {
        float l = lsum[r];
#pragma unroll
        for (int off = 1; off < 16; off <<= 1) l += __shfl_xor(l, off);
        float inv = 1.0f / l;
        int sg = qr0 + quad * 4 + r;
        size_t rowoff = ((size_t)(bb * 2048 + sg)) * 1024 + hh * 64;
#pragma unroll
        for (int df = 0; df < 4; df++) attO[rowoff + df * 16 + c15] = f2b(o[df][r] * inv);
    }
#undef ATTN_STAGE
}

// ---------------- launcher ----------------
extern "C" void kernel_launch(void* const* d_in, const int* in_sizes, int n_in,
                              void* d_out, int out_size, void* d_ws, size_t ws_size,
                              hipStream_t stream) {
    const float* x = (const float*)d_in[0];
    const float* ln1g = (const float*)d_in[1];
    const float* ln1b = (const float*)d_in[2];
    const float* Wq = (const float*)d_in[3];
    const float* bq = (const float*)d_in[4];
    const float* Wk = (const float*)d_in[5];
    const float* bk = (const float*)d_in[6];
    const float* Wv = (const float*)d_in[7];
    const float* bv = (const float*)d_in[8];
    const float* Wo = (const float*)d_in[9];
    const float* bo = (const float*)d_in[10];
    const float* ln2g = (const float*)d_in[11];
    const float* ln2b = (const float*)d_in[12];
    const float* W1 = (const float*)d_in[13];
    const float* b1 = (const float*)d_in[14];
    const float* W2 = (const float*)d_in[15];
    const float* b2 = (const float*)d_in[16];
    float* out = (float*)d_out;

    char* ws = (char*)d_ws;
    u16* wqkvT = (u16*)(ws + 0);              // [3072][1024] bf16, 6 MB
    u16* woT = (u16*)(ws + 6291456);          // [1024][1024], 2 MB
    u8* w1T8 = (u8*)(ws + 8388608);           // [4096][1024] fp8 x32, k-interleaved, 4 MB
    u8* w2T8 = (u8*)(ws + 16777216);          // [1024][4096] fp8 x64, k-interleaved, 4 MB
    u16* h = (u16*)(ws + 25165824);           // ln1 out bf16 [4096][1024], 8 MB
    u8* h8 = (u8*)(ws + 25165824);            // ln2 out fp8 k-interleaved, 4 MB (reuse)
    float* x1 = (float*)(ws + 33554432);      // [4096][1024] fp32, 16 MB
    u16* Qb = (u16*)(ws + 50331648);          // [32 bh][2048][64], 8 MB
    u16* Kb = (u16*)(ws + 58720256);          // 8 MB
    u16* Vb = (u16*)(ws + 67108864);          // 8 MB (later reused as aO)
    u16* VbT = (u16*)(ws + 75497472);         // [32 bh][64][2048'] permuted, 8 MB
    u16* aO = Vb;
    u8* mid8 = (u8*)(ws + 50331648);          // [4096][4096] fp8 k-interleaved, 16 MB

    transpose_all<<<12288, dim3(32, 8), 0, stream>>>(Wq, Wk, Wv, Wo, W1, W2, wqkvT, woT,
                                                     w1T8, w2T8);

    ln_kernel<0><<<4096, 256, 0, stream>>>(x, ln1g, ln1b, h);

    gemm_qkv_kernel<<<dim3(24, 32), 256, 0, stream>>>(h, wqkvT, bq, bk, bv, Qb, 3072, 1024);

    vtrans_kernel<<<dim3(32, 32), 256, 0, stream>>>(Vb, VbT);

    attn_kernel<<<dim3(32, 32), 256, 0, stream>>>(Qb, Kb, VbT, aO);

    gemm64_kernel<<<dim3(16, 32), 256, 0, stream>>>(aO, woT, bo, x1, x, 1024, 1024);

    ln_kernel<1><<<4096, 256, 0, stream>>>(x1, ln2g, ln2b, h8);

    // W1 + GELU: fp8 A (h8) x fp8 B (w1T8 x32) -> fp8 mid8 (k-interleaved)
    gemm_fp8_kernel<EPI_GELU><<<dim3(64, 32), 256, 0, stream>>>(
        h8, w1T8, b1, mid8, nullptr, 4096, 1024, 1.0f / 32.0f);

    // W2: fp8 x fp8 (x64) + residual -> fp32 out
    gemm_fp8_kernel<EPI_RESID><<<dim3(16, 32), 256, 0, stream>>>(
        mid8, w2T8, b2, out, x1, 1024, 4096, 1.0f / 64.0f);
}